// Round 21
// baseline (99.366 us; speedup 1.0000x reference)
//
#include <hip/hip_runtime.h>

// Problem constants
#define BB    2
#define NCTX  2048
#define EDIM  768
#define HH    12
#define DH    64
#define NQKV  2304              // 3 * H * D
#define QSZ   (BB*HH*NCTX*DH)   // elements per tensor (q/k/v/product)
#define GK    768               // K dim of both GEMMs
#define SCALE 0.125f            // 64^-0.5 (exact in bf16)
#define LOG2PI 1.8378770664093453f

typedef __bf16 bf16x8 __attribute__((ext_vector_type(8)));
typedef __bf16 bf16x4 __attribute__((ext_vector_type(4)));
typedef float  f32x4  __attribute__((ext_vector_type(4)));
typedef float  f32x16 __attribute__((ext_vector_type(16)));

// global->LDS direct DMA, 16B per lane; lds base wave-uniform, lane l writes
// base + l*16 (linear). Source address is per-lane.
#define GLOAD_LDS16(g, l)                                      \
  __builtin_amdgcn_global_load_lds(                            \
      (const __attribute__((address_space(1))) void*)(g),      \
      (__attribute__((address_space(3))) void*)(l), 16, 0, 0)

// ---------------------------------------------------------------------------
// P0: ALL input prep in one launch. Grid 3840:
// blocks [0,1536):     x (fp32) -> xbf (bf16), 2048 elems/block
// blocks [1536,3264):  w_qkv [768][2304] -> wqkvT [2304][768] bf16
// blocks [3264,3840):  w_out [768][768]  -> woutT [768][768]  bf16
// ---------------------------------------------------------------------------
__device__ __forceinline__
void cvt_T_tile(const float* __restrict__ W, __bf16* __restrict__ WT,
                int R, int C, int c0, int r0, int t) {
  __shared__ float ts[32][33];
  const int rr = t >> 5, cc = t & 31;
  #pragma unroll
  for (int i = 0; i < 4; ++i)
    ts[rr + i*8][cc] = W[(size_t)(r0 + rr + i*8)*C + c0 + cc];
  __syncthreads();
  #pragma unroll
  for (int i = 0; i < 4; ++i)
    WT[(size_t)(c0 + rr + i*8)*R + r0 + cc] = (__bf16)ts[cc][rr + i*8];
}

__global__ __launch_bounds__(256)
void prep_all(const float* __restrict__ x, __bf16* __restrict__ xbf,
              const float* __restrict__ wqkv, const float* __restrict__ wout,
              __bf16* __restrict__ wqkvT, __bf16* __restrict__ woutT) {
  int b = blockIdx.x;
  if (b < 1536) {
    int i = b*256 + threadIdx.x;           // i < 393216 = 1536*256
    float4 a = *(const float4*)(x + (size_t)i*8);
    float4 c = *(const float4*)(x + (size_t)i*8 + 4);
    bf16x8 o;
    o[0]=(__bf16)a.x; o[1]=(__bf16)a.y; o[2]=(__bf16)a.z; o[3]=(__bf16)a.w;
    o[4]=(__bf16)c.x; o[5]=(__bf16)c.y; o[6]=(__bf16)c.z; o[7]=(__bf16)c.w;
    *(bf16x8*)(xbf + (size_t)i*8) = o;
  } else if (b < 3264) {
    b -= 1536;
    cvt_T_tile(wqkv, wqkvT, GK, NQKV, (b % 72)*32, (b / 72)*32, threadIdx.x);
  } else {
    b -= 3264;
    cvt_T_tile(wout, woutT, GK, EDIM, (b % 24)*32, (b / 24)*32, threadIdx.x);
  }
}

// ---------------------------------------------------------------------------
// Shared GEMM core (unchanged from round 12): 128x128 tile, BK=32, THREE LDS
// buffers, prefetch distance 2, counted vmcnt, raw s_barrier.
// ---------------------------------------------------------------------------
#define GSTAGE(t_, b_) do {                                                  \
    _Pragma("unroll")                                                        \
    for (int i_ = 0; i_ < 2; ++i_) {                                         \
      GLOAD_LDS16(Asrc + (size_t)i_*16*GK + (size_t)(t_)*32,                 \
                  dstA + (b_)*16384 + i_*1024);                              \
      GLOAD_LDS16(Bsrc + (size_t)i_*16*GK + (size_t)(t_)*32,                 \
                  dstB + (b_)*16384 + i_*1024);                              \
    } } while (0)

#define GITER(ki_, c_) do {                                                  \
    if ((ki_) < GK/32 - 1)                                                   \
      asm volatile("s_waitcnt vmcnt(4)" ::: "memory");                       \
    else                                                                     \
      asm volatile("s_waitcnt vmcnt(0)" ::: "memory");                       \
    __builtin_amdgcn_s_barrier();                                            \
    asm volatile("" ::: "memory");                                           \
    if ((ki_) + 2 < GK/32) GSTAGE((ki_) + 2, ((c_) + 2) % 3);                \
    const char* Asc = smem + (c_)*16384;                                     \
    const char* Bsc = Asc + 8192;                                            \
    bf16x8 af[4], bf[4];                                                     \
    _Pragma("unroll")                                                        \
    for (int mf = 0; mf < 4; ++mf) {                                         \
      int m = wr*64 + mf*16 + l15;                                           \
      af[mf] = *(const bf16x8*)(Asc + m*64 + ((g*16) ^ (((m>>1)&3)<<4)));    \
    }                                                                        \
    _Pragma("unroll")                                                        \
    for (int nf = 0; nf < 4; ++nf) {                                         \
      int n = wc*64 + nf*16 + l15;                                           \
      bf[nf] = *(const bf16x8*)(Bsc + n*64 + ((g*16) ^ (((n>>1)&3)<<4)));    \
    }                                                                        \
    __builtin_amdgcn_s_setprio(1);                                           \
    _Pragma("unroll")                                                        \
    for (int mf = 0; mf < 4; ++mf)                                           \
      _Pragma("unroll")                                                      \
      for (int nf = 0; nf < 4; ++nf)                                         \
        acc[mf][nf] = __builtin_amdgcn_mfma_f32_16x16x32_bf16(               \
            af[mf], bf[nf], acc[mf][nf], 0, 0, 0);                           \
    __builtin_amdgcn_s_setprio(0);                                           \
  } while (0)

#define GEMM_CORE(Aa, Bb, acc)                                               \
  const int lane = tid & 63, w = tid >> 6;                                   \
  const int l15 = lane & 15, g = lane >> 4;                                  \
  const int wr = w >> 1, wc = w & 1;                                         \
  const int lrow16 = lane >> 2;                                              \
  const int lsl = (lane & 3) ^ ((lane >> 3) & 3);                            \
  f32x4 acc[4][4];                                                           \
  _Pragma("unroll")                                                          \
  for (int i = 0; i < 4; ++i)                                                \
    _Pragma("unroll")                                                        \
    for (int j = 0; j < 4; ++j) acc[i][j] = (f32x4){0.f,0.f,0.f,0.f};        \
  const __bf16* Asrc = (Aa) + (size_t)(w*32 + lrow16)*GK + lsl*8;            \
  const __bf16* Bsrc = (Bb) + (size_t)(w*32 + lrow16)*GK + lsl*8;            \
  char* dstA = smem + w*2048;                                                \
  char* dstB = smem + 8192 + w*2048;                                         \
  GSTAGE(0, 0);                                                              \
  GSTAGE(1, 1);                                                              \
  for (int kb = 0; kb < GK/96; ++kb) {    /* 24 iters = 8 x 3 */             \
    GITER(kb*3 + 0, 0);                                                      \
    GITER(kb*3 + 1, 1);                                                      \
    GITER(kb*3 + 2, 2);                                                      \
  }

// ---------------------------------------------------------------------------
// K1: qkv GEMM. Grid 576 = 8 XCD x (8 mb x 9 nb). Epilogue scatters bf16:
// q*SCALE, k (b,h,n,d) scalar (d-strided), v^T (b,h,d,n) with PACKED 8B
// stores (4 consecutive ii per acc quad).
// ---------------------------------------------------------------------------
__global__ __launch_bounds__(256)
void gemm_qkv_mfma(const __bf16* __restrict__ A, const __bf16* __restrict__ BT,
                   __bf16* __restrict__ qb, __bf16* __restrict__ kb,
                   __bf16* __restrict__ vtb) {
  __shared__ __align__(16) char smem[3*16384];
  const int tid = threadIdx.x;
  const int xcd = blockIdx.x & 7, local = blockIdx.x >> 3;   // local 0..71
  const int mb = (xcd & 3)*8 + local/9;                      // 0..31
  const int nb = (xcd >> 2)*9 + local%9;                     // 0..17
  const int m0 = mb*128, n0 = nb*128;
  GEMM_CORE(A + (size_t)m0*GK, BT + (size_t)n0*GK, acc)
  #pragma unroll
  for (int mf = 0; mf < 4; ++mf) {
    const int m0r = m0 + wr*64 + mf*16 + g*4;   // 4 consecutive m, same b_
    const int b_  = m0r >> 11, ii0 = m0r & 2047;
    #pragma unroll
    for (int nf = 0; nf < 4; ++nf) {
      const int c = n0 + wc*64 + nf*16 + l15;
      const int t = c / 768;
      const int rem = c - t*768;
      const int head = rem >> 6, dd = rem & 63;
      if (t == 0) {
        #pragma unroll
        for (int r = 0; r < 4; ++r)
          qb[((size_t)(b_*HH + head)*NCTX + ii0 + r)*DH + dd] =
              (__bf16)(acc[mf][nf][r] * SCALE);
      } else if (t == 1) {
        #pragma unroll
        for (int r = 0; r < 4; ++r)
          kb[((size_t)(b_*HH + head)*NCTX + ii0 + r)*DH + dd] =
              (__bf16)acc[mf][nf][r];
      } else {
        bf16x4 pv;
        pv[0] = (__bf16)acc[mf][nf][0];
        pv[1] = (__bf16)acc[mf][nf][1];
        pv[2] = (__bf16)acc[mf][nf][2];
        pv[3] = (__bf16)acc[mf][nf][3];
        *(bf16x4*)(vtb + ((size_t)(b_*HH + head)*DH + dd)*NCTX + ii0) = pv;
      }
    }
  }
}

// ---------------------------------------------------------------------------
// K2: bf16 flash attention (r20 pipeline, byte-identical staging/tiles)
// with ONE contained change: l is computed on the VALU instead of MFMA.
// After swapped QK^T each lane holds its q-row's 16 exp values in fp32
// (keys hi*8+{0..7} U 16+hi*8+{0..7} of the wk-half), so l = running fp32
// tree-sum (lsum) + one shfl_xor(32) at the end + a 256-float LDS
// redistribute in the combine (VALU-l is in lane-q layout; the divide
// needs C-row layout). Deletes 2 of 10 MFMAs per tile (and the lacc
// serial chain); P/PV math unchanged.
// ---------------------------------------------------------------------------
__global__ __launch_bounds__(512)
void attn_mfma(const __bf16* __restrict__ Q, const __bf16* __restrict__ K,
               const __bf16* __restrict__ Vg, float* __restrict__ P) {
  __shared__ __align__(16) char smem[3*16384];  // 3 bufs x (K 8KB + V^T 8KB)
  const int id  = blockIdx.x;                   // 0..383
  const int xcd = id & 7;
  const int jj  = id >> 3;                      // 0..47
  const int bh  = xcd*3 + (jj >> 4);            // 3 heads per XCD
  const int q0  = (jj & 15) * 128;
  const int tid = threadIdx.x;
  const int w = tid >> 6, lane = tid & 63;
  const int wq = w & 3, wk = w >> 2;
  const int l31 = lane & 31, hi = lane >> 5;
  const __bf16* Qb = Q  + (size_t)bh * NCTX * DH;
  const __bf16* Kb = K  + (size_t)bh * NCTX * DH;
  const __bf16* Vb = Vg + (size_t)bh * DH * NCTX;   // [d][n]

  bf16x8 qa[4];
  {
    const __bf16* qr = Qb + (size_t)(q0 + wq*32 + l31)*DH + hi*8;
    #pragma unroll
    for (int s = 0; s < 4; ++s) qa[s] = *(const bf16x8*)(qr + s*16);
  }

  f32x16 oacc[2], zero16;
  #pragma unroll
  for (int i = 0; i < 16; ++i)
    { oacc[0][i] = 0.f; oacc[1][i] = 0.f; zero16[i] = 0.f; }
  float lsum = 0.f;                    // fp32 softmax denom partial (lane-q)

  const int lrow  = lane >> 3;               // 0..7
  const int lslot = (lane & 7) ^ lrow;       // inverse-swizzled 16B slot
  const bool isK = (w < 4);
  const int wg = isK ? w : (w - 4);
  const __bf16* src0 = isK ? (Kb + (size_t)(wg*16 + lrow)*DH   + lslot*8)
                           : (Vb + (size_t)(wg*16 + lrow)*NCTX + lslot*8);
  const int dstoff = (isK ? 0 : 8192) + wg*2048;

  // per-tile stage: 2 gloads/wave (16 rows of K, or 16 d-rows of V^T)
  #define STAGE(kk_, b_) do {                                                 \
    char* sb = smem + (b_)*16384 + dstoff;                                    \
    if (isK) {                                                                \
      GLOAD_LDS16(src0 + (size_t)(kk_)*DH,          sb);                      \
      GLOAD_LDS16(src0 + (size_t)(kk_)*DH + 512,    sb + 1024);               \
    } else {                                                                  \
      GLOAD_LDS16(src0 + (kk_),                     sb);                      \
      GLOAD_LDS16(src0 + (kk_) + 8*NCTX,            sb + 1024);               \
    }                                                                         \
  } while (0)

  #define CVTPK(dst, a, b) \
    asm("v_cvt_pk_bf16_f32 %0, %1, %2" : "=v"(dst) : "v"(a), "v"(b))

  #define ATTN_TILE(TB) do {                                                  \
    const char* Kl = (TB);                                                    \
    const char* Vt = (TB) + 8192;                                             \
    f32x16 sacc;                                                              \
    __builtin_amdgcn_s_setprio(1);                                            \
    {                                                                         \
      const int key = wk*32 + l31;                                            \
      const char* kbase = Kl + key*128;                                       \
      const int swz = (key&7) << 4;                                           \
      bf16x8 kf = *(const bf16x8*)(kbase + ((hi*16) ^ swz));                  \
      sacc = __builtin_amdgcn_mfma_f32_32x32x16_bf16(kf, qa[0], zero16, 0, 0, 0); \
      _Pragma("unroll")                                                       \
      for (int s = 1; s < 4; ++s) {                                           \
        kf = *(const bf16x8*)(kbase + ((s*32 + hi*16) ^ swz));                \
        sacc = __builtin_amdgcn_mfma_f32_32x32x16_bf16(kf, qa[s], sacc, 0, 0, 0); \
      }                                                                       \
    }                                                                         \
    __builtin_amdgcn_s_setprio(0);                                            \
    unsigned px0, px1, px2, px3, px4, px5, px6, px7;                          \
    {                                                                         \
      float e[16];                                                            \
      _Pragma("unroll")                                                       \
      for (int r = 0; r < 16; ++r) e[r] = __expf(sacc[r]);                    \
      lsum += (((e[0]+e[1])+(e[2]+e[3])) + ((e[4]+e[5])+(e[6]+e[7])))         \
            + (((e[8]+e[9])+(e[10]+e[11])) + ((e[12]+e[13])+(e[14]+e[15])));  \
      CVTPK(px0, e[0],  e[1]);  CVTPK(px1, e[2],  e[3]);                      \
      CVTPK(px2, e[4],  e[5]);  CVTPK(px3, e[6],  e[7]);                      \
      CVTPK(px4, e[8],  e[9]);  CVTPK(px5, e[10], e[11]);                     \
      CVTPK(px6, e[12], e[13]); CVTPK(px7, e[14], e[15]);                     \
      asm("v_permlane32_swap_b32 %0, %1" : "+v"(px0), "+v"(px2));             \
      asm("v_permlane32_swap_b32 %0, %1" : "+v"(px1), "+v"(px3));             \
      asm("v_permlane32_swap_b32 %0, %1" : "+v"(px4), "+v"(px6));             \
      asm("v_permlane32_swap_b32 %0, %1" : "+v"(px5), "+v"(px7));             \
    }                                                                         \
    union PF { unsigned u[4]; bf16x8 v; };                                    \
    PF pf0, pf1;                                                              \
    pf0.u[0]=px0; pf0.u[1]=px1; pf0.u[2]=px2; pf0.u[3]=px3;                   \
    pf1.u[0]=px4; pf1.u[1]=px5; pf1.u[2]=px6; pf1.u[3]=px7;                   \
    __builtin_amdgcn_s_setprio(1);                                            \
    _Pragma("unroll")                                                         \
    for (int s = 0; s < 2; ++s) {                                             \
      bf16x8 pf = s ? pf1.v : pf0.v;                                          \
      _Pragma("unroll")                                                       \
      for (int nf = 0; nf < 2; ++nf) {                                        \
        int d = nf*32 + l31;                                                  \
        bf16x8 vf = *(const bf16x8*)(Vt + d*128 +                             \
            (((wk*32 + s*16 + hi*8)*2) ^ ((d&7)<<4)));                        \
        oacc[nf] = __builtin_amdgcn_mfma_f32_32x32x16_bf16(pf, vf, oacc[nf], 0, 0, 0); \
      }                                                                       \
    }                                                                         \
    __builtin_amdgcn_s_setprio(0);                                            \
  } while (0)

  // counted-vmcnt pipeline (GEMM-proven pattern), 32 tiles of 64 keys
  #define AITER(t_, c_) do {                                                  \
    if ((t_) < 31) asm volatile("s_waitcnt vmcnt(2)" ::: "memory");           \
    else           asm volatile("s_waitcnt vmcnt(0)" ::: "memory");           \
    __builtin_amdgcn_s_barrier();                                             \
    asm volatile("" ::: "memory");                                            \
    if ((t_) + 2 < 32) STAGE(((t_)+2)*64, ((c_)+2)%3);                        \
    ATTN_TILE(smem + (c_)*16384);                                             \
  } while (0)

  STAGE(0, 0);
  STAGE(64, 1);
  for (int tb = 0; tb < 30; tb += 3) {
    AITER(tb+0, 0);
    AITER(tb+1, 1);
    AITER(tb+2, 2);
  }
  AITER(30, 0);
  AITER(31, 1);
  #undef AITER
  #undef ATTN_TILE
  #undef STAGE
  #undef CVTPK

  // complete l across the two hi key-subsets (lanes l and l^32 hold the
  // same q = l31; together they cover the wk-half's 32 keys)
  lsum += __shfl_xor(lsum, 32);

  // ---- combine wk halves via LDS scratch, divide, store ----
  __syncthreads();                       // all tile reads done; smem reusable
  float* scrO  = (float*)smem;           // 32KB: [wq][nf][r][lane]
  float* scrLv = (float*)(smem + 32768); // 1KB: [wk][wq*32 + q(l31)]
  if (hi == 0)
    scrLv[wk*128 + wq*32 + l31] = lsum;  // both wk halves publish l
  if (wk == 1) {
    #pragma unroll
    for (int nf = 0; nf < 2; ++nf)
      #pragma unroll
      for (int r = 0; r < 16; ++r)
        scrO[((wq*2 + nf)*16 + r)*64 + lane] = oacc[nf][r];
  }
  __syncthreads();
  if (wk == 0) {
    #pragma unroll
    for (int r = 0; r < 16; ++r) {
      int crow = (r&3) + 8*(r>>2) + 4*hi;
      float lt = scrLv[wq*32 + crow] + scrLv[128 + wq*32 + crow];
      float linv = 1.0f / lt;
      int q = q0 + wq*32 + crow;
      #pragma unroll
      for (int nf = 0; nf < 2; ++nf) {
        float o = oacc[nf][r] + scrO[((wq*2 + nf)*16 + r)*64 + lane];
        P[((size_t)bh*NCTX + q)*DH + nf*32 + l31] = o * linv;
      }
    }
  }
}

// ---------------------------------------------------------------------------
// K3: cross-head stats + log-prob scaling. (unchanged)
// ---------------------------------------------------------------------------
__global__ __launch_bounds__(256)
void stats_scale(const float* __restrict__ P, __bf16* __restrict__ Pbf) {
  const int bi = blockIdx.x*4 + (threadIdx.x >> 6);   // 0..4095
  const int b_ = bi >> 11, i = bi & 2047;
  const int d = threadIdx.x & 63;
  const size_t hstride = (size_t)NCTX * DH;
  const size_t base = ((size_t)(b_*HH) * NCTX + i) * DH + d;
  float x[HH];
  #pragma unroll
  for (int h = 0; h < HH; ++h) x[h] = P[base + h*hstride];
  float sum = 0.f;
  #pragma unroll
  for (int h = 0; h < HH; ++h) sum += x[h];
  float mean = sum * (1.0f/12.0f);
  float ss = 0.f;
  #pragma unroll
  for (int h = 0; h < HH; ++h) { float t = x[h]-mean; ss += t*t; }
  float var = ss * (1.0f/11.0f);        // ddof=1
  float lv = logf(var);
  float inv = 0.25f / var;
  __bf16* orow = Pbf + (size_t)bi * GK + d;
  #pragma unroll
  for (int h = 0; h < HH; ++h) {
    float t = x[h] - mean;
    float part = -0.5f*LOG2PI - lv + t*t*inv;
    #pragma unroll
    for (int off = 32; off; off >>= 1) part += __shfl_xor(part, off);
    orow[h*DH] = (__bf16)(part * x[h]);   // lp_h * product, GEMM-A layout
  }
}

// ---------------------------------------------------------------------------
// K4: out = Pbf @ woutT^T + b_out  (unchanged from round 12).
// ---------------------------------------------------------------------------
__global__ __launch_bounds__(256)
void gemm_out_mfma(const __bf16* __restrict__ A, const __bf16* __restrict__ BT,
                   const float* __restrict__ bias, float* __restrict__ out) {
  __shared__ __align__(16) char smem[3*16384];
  const int tid = threadIdx.x;
  const int xcd = blockIdx.x & 7, local = blockIdx.x >> 3;   // local 0..23
  const int mb = (xcd & 3)*8 + local/3;                      // 0..31
  const int nb = (xcd >> 2)*3 + local%3;                     // 0..5
  const int m0 = mb*128, n0 = nb*128;
  GEMM_CORE(A + (size_t)m0*GK, BT + (size_t)n0*GK, acc)
  #pragma unroll
  for (int mf = 0; mf < 4; ++mf)
    #pragma unroll
    for (int nf = 0; nf < 4; ++nf)
      #pragma unroll
      for (int r = 0; r < 4; ++r) {
        int m = m0 + wr*64 + mf*16 + g*4 + r;
        int c = n0 + wc*64 + nf*16 + l15;
        out[(size_t)m*EDIM + c] = acc[mf][nf][r] + bias[c];
      }
}

// ---------------------------------------------------------------------------
extern "C" void kernel_launch(void* const* d_in, const int* in_sizes, int n_in,
                              void* d_out, int out_size, void* d_ws, size_t ws_size,
                              hipStream_t stream) {
  const float* x     = (const float*)d_in[0];
  const float* w_qkv = (const float*)d_in[1];
  const float* w_out = (const float*)d_in[2];
  const float* b_out = (const float*)d_in[3];
  float* out = (float*)d_out;

  __bf16* xbf   = (__bf16*)d_ws;                  // [4096][768]
  __bf16* wqkvT = xbf   + (size_t)BB*NCTX*GK;     // [2304][768]
  __bf16* woutT = wqkvT + (size_t)NQKV*GK;        // [768][768]
  __bf16* qb    = woutT + (size_t)EDIM*GK;
  __bf16* kb    = qb  + (size_t)QSZ;
  __bf16* vtb   = kb  + (size_t)QSZ;              // (b,h,d,n)
  __bf16* Pbf   = vtb + (size_t)QSZ;              // [4096][768] scaled product
  float*  Pf    = (float*)(Pbf + (size_t)QSZ);    // (b,h,n,d) product

  prep_all<<<dim3(3840), 256, 0, stream>>>(x, xbf, w_qkv, w_out, wqkvT, woutT);
  gemm_qkv_mfma<<<dim3(576), 256, 0, stream>>>(xbf, wqkvT, qb, kb, vtb);
  attn_mfma<<<dim3(384), 512, 0, stream>>>(qb, kb, vtb, Pf);
  stats_scale<<<dim3(BB*NCTX/4), 256, 0, stream>>>(Pf, Pbf);
  gemm_out_mfma<<<dim3(192), 256, 0, stream>>>(Pbf, woutT, b_out, out);
}

// Round 22
// 95.634 us; speedup vs baseline: 1.0390x; 1.0390x over previous
//
#include <hip/hip_runtime.h>

// Problem constants
#define BB    2
#define NCTX  2048
#define EDIM  768
#define HH    12
#define DH    64
#define NQKV  2304              // 3 * H * D
#define QSZ   (BB*HH*NCTX*DH)   // elements per tensor (q/k/v/product)
#define GK    768               // K dim of both GEMMs
#define SCALE 0.125f            // 64^-0.5 (exact in bf16)
#define LOG2PI 1.8378770664093453f

typedef __bf16 bf16x8 __attribute__((ext_vector_type(8)));
typedef __bf16 bf16x4 __attribute__((ext_vector_type(4)));
typedef float  f32x4  __attribute__((ext_vector_type(4)));
typedef float  f32x16 __attribute__((ext_vector_type(16)));

// global->LDS direct DMA, 16B per lane; lds base wave-uniform, lane l writes
// base + l*16 (linear). Source address is per-lane.
#define GLOAD_LDS16(g, l)                                      \
  __builtin_amdgcn_global_load_lds(                            \
      (const __attribute__((address_space(1))) void*)(g),      \
      (__attribute__((address_space(3))) void*)(l), 16, 0, 0)

// ---------------------------------------------------------------------------
// P0: ALL input prep in one launch. Grid 3840:
// blocks [0,1536):     x (fp32) -> xbf (bf16), 2048 elems/block
// blocks [1536,3264):  w_qkv [768][2304] -> wqkvT [2304][768] bf16
// blocks [3264,3840):  w_out [768][768]  -> woutT [768][768]  bf16
// ---------------------------------------------------------------------------
__device__ __forceinline__
void cvt_T_tile(const float* __restrict__ W, __bf16* __restrict__ WT,
                int R, int C, int c0, int r0, int t) {
  __shared__ float ts[32][33];
  const int rr = t >> 5, cc = t & 31;
  #pragma unroll
  for (int i = 0; i < 4; ++i)
    ts[rr + i*8][cc] = W[(size_t)(r0 + rr + i*8)*C + c0 + cc];
  __syncthreads();
  #pragma unroll
  for (int i = 0; i < 4; ++i)
    WT[(size_t)(c0 + rr + i*8)*R + r0 + cc] = (__bf16)ts[cc][rr + i*8];
}

__global__ __launch_bounds__(256)
void prep_all(const float* __restrict__ x, __bf16* __restrict__ xbf,
              const float* __restrict__ wqkv, const float* __restrict__ wout,
              __bf16* __restrict__ wqkvT, __bf16* __restrict__ woutT) {
  int b = blockIdx.x;
  if (b < 1536) {
    int i = b*256 + threadIdx.x;           // i < 393216 = 1536*256
    float4 a = *(const float4*)(x + (size_t)i*8);
    float4 c = *(const float4*)(x + (size_t)i*8 + 4);
    bf16x8 o;
    o[0]=(__bf16)a.x; o[1]=(__bf16)a.y; o[2]=(__bf16)a.z; o[3]=(__bf16)a.w;
    o[4]=(__bf16)c.x; o[5]=(__bf16)c.y; o[6]=(__bf16)c.z; o[7]=(__bf16)c.w;
    *(bf16x8*)(xbf + (size_t)i*8) = o;
  } else if (b < 3264) {
    b -= 1536;
    cvt_T_tile(wqkv, wqkvT, GK, NQKV, (b % 72)*32, (b / 72)*32, threadIdx.x);
  } else {
    b -= 3264;
    cvt_T_tile(wout, woutT, GK, EDIM, (b % 24)*32, (b / 24)*32, threadIdx.x);
  }
}

// ---------------------------------------------------------------------------
// Shared GEMM core: 128x128 tile, BK=32, THREE LDS buffers, prefetch
// distance 2, counted vmcnt, raw s_barrier.
// ---------------------------------------------------------------------------
#define GSTAGE(t_, b_) do {                                                  \
    _Pragma("unroll")                                                        \
    for (int i_ = 0; i_ < 2; ++i_) {                                         \
      GLOAD_LDS16(Asrc + (size_t)i_*16*GK + (size_t)(t_)*32,                 \
                  dstA + (b_)*16384 + i_*1024);                              \
      GLOAD_LDS16(Bsrc + (size_t)i_*16*GK + (size_t)(t_)*32,                 \
                  dstB + (b_)*16384 + i_*1024);                              \
    } } while (0)

#define GITER(ki_, c_) do {                                                  \
    if ((ki_) < GK/32 - 1)                                                   \
      asm volatile("s_waitcnt vmcnt(4)" ::: "memory");                       \
    else                                                                     \
      asm volatile("s_waitcnt vmcnt(0)" ::: "memory");                       \
    __builtin_amdgcn_s_barrier();                                            \
    asm volatile("" ::: "memory");                                           \
    if ((ki_) + 2 < GK/32) GSTAGE((ki_) + 2, ((c_) + 2) % 3);                \
    const char* Asc = smem + (c_)*16384;                                     \
    const char* Bsc = Asc + 8192;                                            \
    bf16x8 af[4], bf[4];                                                     \
    _Pragma("unroll")                                                        \
    for (int mf = 0; mf < 4; ++mf) {                                         \
      int m = wr*64 + mf*16 + l15;                                           \
      af[mf] = *(const bf16x8*)(Asc + m*64 + ((g*16) ^ (((m>>1)&3)<<4)));    \
    }                                                                        \
    _Pragma("unroll")                                                        \
    for (int nf = 0; nf < 4; ++nf) {                                         \
      int n = wc*64 + nf*16 + l15;                                           \
      bf[nf] = *(const bf16x8*)(Bsc + n*64 + ((g*16) ^ (((n>>1)&3)<<4)));    \
    }                                                                        \
    __builtin_amdgcn_s_setprio(1);                                           \
    _Pragma("unroll")                                                        \
    for (int mf = 0; mf < 4; ++mf)                                           \
      _Pragma("unroll")                                                      \
      for (int nf = 0; nf < 4; ++nf)                                         \
        acc[mf][nf] = __builtin_amdgcn_mfma_f32_16x16x32_bf16(               \
            af[mf], bf[nf], acc[mf][nf], 0, 0, 0);                           \
    __builtin_amdgcn_s_setprio(0);                                           \
  } while (0)

#define GEMM_CORE(Aa, Bb, acc)                                               \
  const int lane = tid & 63, w = tid >> 6;                                   \
  const int l15 = lane & 15, g = lane >> 4;                                  \
  const int wr = w >> 1, wc = w & 1;                                         \
  const int lrow16 = lane >> 2;                                              \
  const int lsl = (lane & 3) ^ ((lane >> 3) & 3);                            \
  f32x4 acc[4][4];                                                           \
  _Pragma("unroll")                                                          \
  for (int i = 0; i < 4; ++i)                                                \
    _Pragma("unroll")                                                        \
    for (int j = 0; j < 4; ++j) acc[i][j] = (f32x4){0.f,0.f,0.f,0.f};        \
  const __bf16* Asrc = (Aa) + (size_t)(w*32 + lrow16)*GK + lsl*8;            \
  const __bf16* Bsrc = (Bb) + (size_t)(w*32 + lrow16)*GK + lsl*8;            \
  char* dstA = smem + w*2048;                                                \
  char* dstB = smem + 8192 + w*2048;                                         \
  GSTAGE(0, 0);                                                              \
  GSTAGE(1, 1);                                                              \
  for (int kb = 0; kb < GK/96; ++kb) {    /* 24 iters = 8 x 3 */             \
    GITER(kb*3 + 0, 0);                                                      \
    GITER(kb*3 + 1, 1);                                                      \
    GITER(kb*3 + 2, 2);                                                      \
  }

// ---------------------------------------------------------------------------
// K1: qkv GEMM. Grid 576 = 8 XCD x (8 mb x 9 nb). Epilogue scatters bf16:
// q*SCALE, k (b,h,n,d) scalar (d-strided), v^T (b,h,d,n) with PACKED 8B
// stores (4 consecutive ii per acc quad).
// ---------------------------------------------------------------------------
__global__ __launch_bounds__(256)
void gemm_qkv_mfma(const __bf16* __restrict__ A, const __bf16* __restrict__ BT,
                   __bf16* __restrict__ qb, __bf16* __restrict__ kb,
                   __bf16* __restrict__ vtb) {
  __shared__ __align__(16) char smem[3*16384];
  const int tid = threadIdx.x;
  const int xcd = blockIdx.x & 7, local = blockIdx.x >> 3;   // local 0..71
  const int mb = (xcd & 3)*8 + local/9;                      // 0..31
  const int nb = (xcd >> 2)*9 + local%9;                     // 0..17
  const int m0 = mb*128, n0 = nb*128;
  GEMM_CORE(A + (size_t)m0*GK, BT + (size_t)n0*GK, acc)
  #pragma unroll
  for (int mf = 0; mf < 4; ++mf) {
    const int m0r = m0 + wr*64 + mf*16 + g*4;   // 4 consecutive m, same b_
    const int b_  = m0r >> 11, ii0 = m0r & 2047;
    #pragma unroll
    for (int nf = 0; nf < 4; ++nf) {
      const int c = n0 + wc*64 + nf*16 + l15;
      const int t = c / 768;
      const int rem = c - t*768;
      const int head = rem >> 6, dd = rem & 63;
      if (t == 0) {
        #pragma unroll
        for (int r = 0; r < 4; ++r)
          qb[((size_t)(b_*HH + head)*NCTX + ii0 + r)*DH + dd] =
              (__bf16)(acc[mf][nf][r] * SCALE);
      } else if (t == 1) {
        #pragma unroll
        for (int r = 0; r < 4; ++r)
          kb[((size_t)(b_*HH + head)*NCTX + ii0 + r)*DH + dd] =
              (__bf16)acc[mf][nf][r];
      } else {
        bf16x4 pv;
        pv[0] = (__bf16)acc[mf][nf][0];
        pv[1] = (__bf16)acc[mf][nf][1];
        pv[2] = (__bf16)acc[mf][nf][2];
        pv[3] = (__bf16)acc[mf][nf][3];
        *(bf16x4*)(vtb + ((size_t)(b_*HH + head)*DH + dd)*NCTX + ii0) = pv;
      }
    }
  }
}

// ---------------------------------------------------------------------------
// K2: bf16 flash attention. 8-wave decode, r14-proven tile macro/combine,
// 3-buffer counted-vmcnt pipeline (vmcnt(2) drains only the current tile's
// 2 gloads/wave, raw s_barrier, prefetch distance 2). l = P @ ones on the
// MFMA pipe. No-max softmax (exact: shift-invariant, |S|max ~ 6).
// ---------------------------------------------------------------------------
__global__ __launch_bounds__(512)
void attn_mfma(const __bf16* __restrict__ Q, const __bf16* __restrict__ K,
               const __bf16* __restrict__ Vg, float* __restrict__ P) {
  __shared__ __align__(16) char smem[3*16384];  // 3 bufs x (K 8KB + V^T 8KB)
  const int id  = blockIdx.x;                   // 0..383
  const int xcd = id & 7;
  const int jj  = id >> 3;                      // 0..47
  const int bh  = xcd*3 + (jj >> 4);            // 3 heads per XCD
  const int q0  = (jj & 15) * 128;
  const int tid = threadIdx.x;
  const int w = tid >> 6, lane = tid & 63;
  const int wq = w & 3, wk = w >> 2;
  const int l31 = lane & 31, hi = lane >> 5;
  const __bf16* Qb = Q  + (size_t)bh * NCTX * DH;
  const __bf16* Kb = K  + (size_t)bh * NCTX * DH;
  const __bf16* Vb = Vg + (size_t)bh * DH * NCTX;   // [d][n]

  bf16x8 qa[4];
  {
    const __bf16* qr = Qb + (size_t)(q0 + wq*32 + l31)*DH + hi*8;
    #pragma unroll
    for (int s = 0; s < 4; ++s) qa[s] = *(const bf16x8*)(qr + s*16);
  }
  bf16x8 ones;
  #pragma unroll
  for (int j = 0; j < 8; ++j) ones[j] = (__bf16)1.0f;

  f32x16 oacc[2], lacc, zero16;
  #pragma unroll
  for (int i = 0; i < 16; ++i)
    { oacc[0][i] = 0.f; oacc[1][i] = 0.f; lacc[i] = 0.f; zero16[i] = 0.f; }

  const int lrow  = lane >> 3;               // 0..7
  const int lslot = (lane & 7) ^ lrow;       // inverse-swizzled 16B slot
  const bool isK = (w < 4);
  const int wg = isK ? w : (w - 4);
  const __bf16* src0 = isK ? (Kb + (size_t)(wg*16 + lrow)*DH   + lslot*8)
                           : (Vb + (size_t)(wg*16 + lrow)*NCTX + lslot*8);
  const int dstoff = (isK ? 0 : 8192) + wg*2048;

  // per-tile stage: 2 gloads/wave (16 rows of K, or 16 d-rows of V^T)
  #define STAGE(kk_, b_) do {                                                 \
    char* sb = smem + (b_)*16384 + dstoff;                                    \
    if (isK) {                                                                \
      GLOAD_LDS16(src0 + (size_t)(kk_)*DH,          sb);                      \
      GLOAD_LDS16(src0 + (size_t)(kk_)*DH + 512,    sb + 1024);               \
    } else {                                                                  \
      GLOAD_LDS16(src0 + (kk_),                     sb);                      \
      GLOAD_LDS16(src0 + (kk_) + 8*NCTX,            sb + 1024);               \
    }                                                                         \
  } while (0)

  #define CVTPK(dst, a, b) \
    asm("v_cvt_pk_bf16_f32 %0, %1, %2" : "=v"(dst) : "v"(a), "v"(b))

  #define ATTN_TILE(TB) do {                                                  \
    const char* Kl = (TB);                                                    \
    const char* Vt = (TB) + 8192;                                             \
    f32x16 sacc;                                                              \
    __builtin_amdgcn_s_setprio(1);                                            \
    {                                                                         \
      const int key = wk*32 + l31;                                            \
      const char* kbase = Kl + key*128;                                       \
      const int swz = (key&7) << 4;                                           \
      bf16x8 kf = *(const bf16x8*)(kbase + ((hi*16) ^ swz));                  \
      sacc = __builtin_amdgcn_mfma_f32_32x32x16_bf16(kf, qa[0], zero16, 0, 0, 0); \
      _Pragma("unroll")                                                       \
      for (int s = 1; s < 4; ++s) {                                           \
        kf = *(const bf16x8*)(kbase + ((s*32 + hi*16) ^ swz));                \
        sacc = __builtin_amdgcn_mfma_f32_32x32x16_bf16(kf, qa[s], sacc, 0, 0, 0); \
      }                                                                       \
    }                                                                         \
    __builtin_amdgcn_s_setprio(0);                                            \
    unsigned px0, px1, px2, px3, px4, px5, px6, px7;                          \
    {                                                                         \
      float e[16];                                                            \
      _Pragma("unroll")                                                       \
      for (int r = 0; r < 16; ++r) e[r] = __expf(sacc[r]);                    \
      CVTPK(px0, e[0],  e[1]);  CVTPK(px1, e[2],  e[3]);                      \
      CVTPK(px2, e[4],  e[5]);  CVTPK(px3, e[6],  e[7]);                      \
      CVTPK(px4, e[8],  e[9]);  CVTPK(px5, e[10], e[11]);                     \
      CVTPK(px6, e[12], e[13]); CVTPK(px7, e[14], e[15]);                     \
      asm("v_permlane32_swap_b32 %0, %1" : "+v"(px0), "+v"(px2));             \
      asm("v_permlane32_swap_b32 %0, %1" : "+v"(px1), "+v"(px3));             \
      asm("v_permlane32_swap_b32 %0, %1" : "+v"(px4), "+v"(px6));             \
      asm("v_permlane32_swap_b32 %0, %1" : "+v"(px5), "+v"(px7));             \
    }                                                                         \
    union PF { unsigned u[4]; bf16x8 v; };                                    \
    PF pf0, pf1;                                                              \
    pf0.u[0]=px0; pf0.u[1]=px1; pf0.u[2]=px2; pf0.u[3]=px3;                   \
    pf1.u[0]=px4; pf1.u[1]=px5; pf1.u[2]=px6; pf1.u[3]=px7;                   \
    __builtin_amdgcn_s_setprio(1);                                            \
    _Pragma("unroll")                                                         \
    for (int s = 0; s < 2; ++s) {                                             \
      bf16x8 pf = s ? pf1.v : pf0.v;                                          \
      lacc = __builtin_amdgcn_mfma_f32_32x32x16_bf16(pf, ones, lacc, 0, 0, 0);\
      _Pragma("unroll")                                                       \
      for (int nf = 0; nf < 2; ++nf) {                                        \
        int d = nf*32 + l31;                                                  \
        bf16x8 vf = *(const bf16x8*)(Vt + d*128 +                             \
            (((wk*32 + s*16 + hi*8)*2) ^ ((d&7)<<4)));                        \
        oacc[nf] = __builtin_amdgcn_mfma_f32_32x32x16_bf16(pf, vf, oacc[nf], 0, 0, 0); \
      }                                                                       \
    }                                                                         \
    __builtin_amdgcn_s_setprio(0);                                            \
  } while (0)

  // counted-vmcnt pipeline (GEMM-proven pattern), 32 tiles of 64 keys
  #define AITER(t_, c_) do {                                                  \
    if ((t_) < 31) asm volatile("s_waitcnt vmcnt(2)" ::: "memory");           \
    else           asm volatile("s_waitcnt vmcnt(0)" ::: "memory");           \
    __builtin_amdgcn_s_barrier();                                             \
    asm volatile("" ::: "memory");                                            \
    if ((t_) + 2 < 32) STAGE(((t_)+2)*64, ((c_)+2)%3);                        \
    ATTN_TILE(smem + (c_)*16384);                                             \
  } while (0)

  STAGE(0, 0);
  STAGE(64, 1);
  for (int tb = 0; tb < 30; tb += 3) {
    AITER(tb+0, 0);
    AITER(tb+1, 1);
    AITER(tb+2, 2);
  }
  AITER(30, 0);
  AITER(31, 1);
  #undef AITER
  #undef ATTN_TILE
  #undef STAGE
  #undef CVTPK

  // ---- combine wk halves via LDS scratch, divide, store ----
  __syncthreads();                       // all tile reads done; smem reusable
  float* scrO = (float*)smem;            // 32KB: [wq][nf][r][lane]
  float* scrL = (float*)(smem + 32768);  // 16KB: [wq][r][lane]
  if (wk == 1) {
    #pragma unroll
    for (int nf = 0; nf < 2; ++nf)
      #pragma unroll
      for (int r = 0; r < 16; ++r)
        scrO[((wq*2 + nf)*16 + r)*64 + lane] = oacc[nf][r];
    #pragma unroll
    for (int r = 0; r < 16; ++r)
      scrL[(wq*16 + r)*64 + lane] = lacc[r];
  }
  __syncthreads();
  if (wk == 0) {
    #pragma unroll
    for (int r = 0; r < 16; ++r) {
      float linv = 1.0f / (lacc[r] + scrL[(wq*16 + r)*64 + lane]);
      int q = q0 + wq*32 + (r&3) + 8*(r>>2) + 4*hi;
      #pragma unroll
      for (int nf = 0; nf < 2; ++nf) {
        float o = oacc[nf][r] + scrO[((wq*2 + nf)*16 + r)*64 + lane];
        P[((size_t)bh*NCTX + q)*DH + nf*32 + l31] = o * linv;
      }
    }
  }
}

// ---------------------------------------------------------------------------
// K3: cross-head stats + log-prob scaling. (unchanged)
// ---------------------------------------------------------------------------
__global__ __launch_bounds__(256)
void stats_scale(const float* __restrict__ P, __bf16* __restrict__ Pbf) {
  const int bi = blockIdx.x*4 + (threadIdx.x >> 6);   // 0..4095
  const int b_ = bi >> 11, i = bi & 2047;
  const int d = threadIdx.x & 63;
  const size_t hstride = (size_t)NCTX * DH;
  const size_t base = ((size_t)(b_*HH) * NCTX + i) * DH + d;
  float x[HH];
  #pragma unroll
  for (int h = 0; h < HH; ++h) x[h] = P[base + h*hstride];
  float sum = 0.f;
  #pragma unroll
  for (int h = 0; h < HH; ++h) sum += x[h];
  float mean = sum * (1.0f/12.0f);
  float ss = 0.f;
  #pragma unroll
  for (int h = 0; h < HH; ++h) { float t = x[h]-mean; ss += t*t; }
  float var = ss * (1.0f/11.0f);        // ddof=1
  float lv = logf(var);
  float inv = 0.25f / var;
  __bf16* orow = Pbf + (size_t)bi * GK + d;
  #pragma unroll
  for (int h = 0; h < HH; ++h) {
    float t = x[h] - mean;
    float part = -0.5f*LOG2PI - lv + t*t*inv;
    #pragma unroll
    for (int off = 32; off; off >>= 1) part += __shfl_xor(part, off);
    orow[h*DH] = (__bf16)(part * x[h]);   // lp_h * product, GEMM-A layout
  }
}

// ---------------------------------------------------------------------------
// K4: out = Pbf @ woutT^T + b_out  (unchanged from round 12).
// ---------------------------------------------------------------------------
__global__ __launch_bounds__(256)
void gemm_out_mfma(const __bf16* __restrict__ A, const __bf16* __restrict__ BT,
                   const float* __restrict__ bias, float* __restrict__ out) {
  __shared__ __align__(16) char smem[3*16384];
  const int tid = threadIdx.x;
  const int xcd = blockIdx.x & 7, local = blockIdx.x >> 3;   // local 0..23
  const int mb = (xcd & 3)*8 + local/3;                      // 0..31
  const int nb = (xcd >> 2)*3 + local%3;                     // 0..5
  const int m0 = mb*128, n0 = nb*128;
  GEMM_CORE(A + (size_t)m0*GK, BT + (size_t)n0*GK, acc)
  #pragma unroll
  for (int mf = 0; mf < 4; ++mf)
    #pragma unroll
    for (int nf = 0; nf < 4; ++nf)
      #pragma unroll
      for (int r = 0; r < 4; ++r) {
        int m = m0 + wr*64 + mf*16 + g*4 + r;
        int c = n0 + wc*64 + nf*16 + l15;
        out[(size_t)m*EDIM + c] = acc[mf][nf][r] + bias[c];
      }
}

// ---------------------------------------------------------------------------
extern "C" void kernel_launch(void* const* d_in, const int* in_sizes, int n_in,
                              void* d_out, int out_size, void* d_ws, size_t ws_size,
                              hipStream_t stream) {
  const float* x     = (const float*)d_in[0];
  const float* w_qkv = (const float*)d_in[1];
  const float* w_out = (const float*)d_in[2];
  const float* b_out = (const float*)d_in[3];
  float* out = (float*)d_out;

  __bf16* xbf   = (__bf16*)d_ws;                  // [4096][768]
  __bf16* wqkvT = xbf   + (size_t)BB*NCTX*GK;     // [2304][768]
  __bf16* woutT = wqkvT + (size_t)NQKV*GK;        // [768][768]
  __bf16* qb    = woutT + (size_t)EDIM*GK;
  __bf16* kb    = qb  + (size_t)QSZ;
  __bf16* vtb   = kb  + (size_t)QSZ;              // (b,h,d,n)
  __bf16* Pbf   = vtb + (size_t)QSZ;              // [4096][768] scaled product
  float*  Pf    = (float*)(Pbf + (size_t)QSZ);    // (b,h,n,d) product

  prep_all<<<dim3(3840), 256, 0, stream>>>(x, xbf, w_qkv, w_out, wqkvT, woutT);
  gemm_qkv_mfma<<<dim3(576), 256, 0, stream>>>(xbf, wqkvT, qb, kb, vtb);
  attn_mfma<<<dim3(384), 512, 0, stream>>>(qb, kb, vtb, Pf);
  stats_scale<<<dim3(BB*NCTX/4), 256, 0, stream>>>(Pf, Pbf);
  gemm_out_mfma<<<dim3(192), 256, 0, stream>>>(Pbf, woutT, b_out, out);
}